// Round 1
// baseline (888.483 us; speedup 1.0000x reference)
//
#include <hip/hip_runtime.h>
#include <hip/hip_bf16.h>

#define N_NODES 100000

// ---------------------------------------------------------------------------
// CSR build: histogram -> scan -> fill
// ---------------------------------------------------------------------------
__global__ __launch_bounds__(256) void hist_kernel(const int* __restrict__ dst,
                                                   int* __restrict__ deg, int E) {
    int e = blockIdx.x * 256 + threadIdx.x;
    if (e < E) atomicAdd(&deg[dst[e]], 1);
}

// single-block scan: 1024 threads, wave shuffle scans + LDS cross-wave
__global__ __launch_bounds__(1024) void scan_kernel(const int* __restrict__ deg,
                                                    int* __restrict__ row_ptr,
                                                    int* __restrict__ cursor,
                                                    float* __restrict__ inv_deg, int N) {
    __shared__ int wsums[16];
    __shared__ int s_carry;
    int tid = threadIdx.x;
    int lane = tid & 63, wave = tid >> 6;
    if (tid == 0) s_carry = 0;
    __syncthreads();
    for (int base = 0; base < N; base += 1024) {
        int i = base + tid;
        int v = (i < N) ? deg[i] : 0;
        // inclusive scan within wave (64 lanes)
        int x = v;
        #pragma unroll
        for (int off = 1; off < 64; off <<= 1) {
            int y = __shfl_up(x, off, 64);
            if (lane >= off) x += y;
        }
        if (lane == 63) wsums[wave] = x;
        __syncthreads();
        int wave_off = 0;
        for (int w = 0; w < wave; ++w) wave_off += wsums[w];
        int incl = x + wave_off;
        int excl = incl - v;
        int carry = s_carry;
        if (i < N) {
            int rp = carry + excl;
            row_ptr[i] = rp;
            cursor[i]  = rp;
            inv_deg[i] = 1.0f / (float)(v > 0 ? v : 1);
        }
        __syncthreads();
        if (tid == 1023) s_carry = carry + incl;
        __syncthreads();
    }
    if (tid == 0) row_ptr[N] = s_carry;
}

__global__ __launch_bounds__(256) void fill_kernel(const int* __restrict__ src,
                                                   const int* __restrict__ dst,
                                                   int* __restrict__ cursor,
                                                   int* __restrict__ edge_src, int E) {
    int e = blockIdx.x * 256 + threadIdx.x;
    if (e < E) {
        int d = dst[e];
        int p = atomicAdd(&cursor[d], 1);
        edge_src[p] = src[e];
    }
}

// ---------------------------------------------------------------------------
// GEMM: Y[M,Nout] = X[M,K] @ W[K,Nout] (+ bias). 64x64 tile, 256 thr, 4x4 acc.
// K multiple of 64.
// ---------------------------------------------------------------------------
__global__ __launch_bounds__(256) void gemm_kernel(const float* __restrict__ X,
                                                   const float* __restrict__ W,
                                                   const float* __restrict__ bias,
                                                   float* __restrict__ Y,
                                                   int M, int K, int Nout) {
    __shared__ float As[64][68];
    __shared__ float Bs[64][68];
    int tid = threadIdx.x;
    int tr = tid >> 4, tc = tid & 15;       // 16x16 thread grid
    int m0 = blockIdx.x * 64, n0 = blockIdx.y * 64;
    float acc[4][4] = {{0}};

    for (int k0 = 0; k0 < K; k0 += 64) {
        #pragma unroll
        for (int i = 0; i < 4; ++i) {
            int idx = tid + i * 256;        // 0..1023 float4 slots
            int m  = idx >> 4, kq = idx & 15;
            int gm = m0 + m;
            float4 a = (gm < M) ? *(const float4*)&X[(size_t)gm * K + k0 + 4 * kq]
                                : make_float4(0.f, 0.f, 0.f, 0.f);
            *(float4*)&As[m][4 * kq] = a;
            // B tile: same linearization, row=k-within-tile, col-quad
            int kk = idx >> 4, nq = idx & 15;
            float4 b = *(const float4*)&W[(size_t)(k0 + kk) * Nout + n0 + 4 * nq];
            *(float4*)&Bs[kk][4 * nq] = b;
        }
        __syncthreads();

        #pragma unroll
        for (int kq = 0; kq < 16; ++kq) {
            float4 a0 = *(const float4*)&As[4 * tr + 0][4 * kq];
            float4 a1 = *(const float4*)&As[4 * tr + 1][4 * kq];
            float4 a2 = *(const float4*)&As[4 * tr + 2][4 * kq];
            float4 a3 = *(const float4*)&As[4 * tr + 3][4 * kq];
            float4 b0 = *(const float4*)&Bs[4 * kq + 0][4 * tc];
            float4 b1 = *(const float4*)&Bs[4 * kq + 1][4 * tc];
            float4 b2 = *(const float4*)&Bs[4 * kq + 2][4 * tc];
            float4 b3 = *(const float4*)&Bs[4 * kq + 3][4 * tc];
#define FMA4(i, av, bv)                                                        \
            acc[i][0] += (av) * (bv).x; acc[i][1] += (av) * (bv).y;            \
            acc[i][2] += (av) * (bv).z; acc[i][3] += (av) * (bv).w;
            FMA4(0, a0.x, b0) FMA4(0, a0.y, b1) FMA4(0, a0.z, b2) FMA4(0, a0.w, b3)
            FMA4(1, a1.x, b0) FMA4(1, a1.y, b1) FMA4(1, a1.z, b2) FMA4(1, a1.w, b3)
            FMA4(2, a2.x, b0) FMA4(2, a2.y, b1) FMA4(2, a2.z, b2) FMA4(2, a2.w, b3)
            FMA4(3, a3.x, b0) FMA4(3, a3.y, b1) FMA4(3, a3.z, b2) FMA4(3, a3.w, b3)
#undef FMA4
        }
        __syncthreads();
    }

    float4 bv = make_float4(0.f, 0.f, 0.f, 0.f);
    if (bias) bv = *(const float4*)&bias[n0 + 4 * tc];
    #pragma unroll
    for (int i = 0; i < 4; ++i) {
        int gm = m0 + 4 * tr + i;
        if (gm < M) {
            float4 o;
            o.x = acc[i][0] + bv.x; o.y = acc[i][1] + bv.y;
            o.z = acc[i][2] + bv.z; o.w = acc[i][3] + bv.w;
            *(float4*)&Y[(size_t)gm * Nout + n0 + 4 * tc] = o;
        }
    }
}

// ---------------------------------------------------------------------------
// Aggregate: out[n,f] = act( S[n,f] + inv_deg[n] * sum_{e in in(n)} Z[src_e, f] )
// ACT: 0 = relu, 1 = softmax over D (requires D==64, one wave per node)
// ---------------------------------------------------------------------------
template <int D, int ACT>
__global__ __launch_bounds__(256) void agg_kernel(const float* __restrict__ S,
                                                  const float* __restrict__ Z,
                                                  const int* __restrict__ row_ptr,
                                                  const int* __restrict__ edge_src,
                                                  const float* __restrict__ inv_deg,
                                                  float* __restrict__ out, int N) {
    constexpr int G = 256 / D;
    int tid = threadIdx.x;
    int g = tid / D, f = tid % D;
    int n = blockIdx.x * G + g;
    if (n >= N) return;
    int beg = row_ptr[n], end = row_ptr[n + 1];
    float a0 = 0.f, a1 = 0.f, a2 = 0.f, a3 = 0.f;
    int j = beg;
    for (; j + 3 < end; j += 4) {
        int s0 = edge_src[j + 0], s1 = edge_src[j + 1];
        int s2 = edge_src[j + 2], s3 = edge_src[j + 3];
        a0 += Z[(size_t)s0 * D + f];
        a1 += Z[(size_t)s1 * D + f];
        a2 += Z[(size_t)s2 * D + f];
        a3 += Z[(size_t)s3 * D + f];
    }
    for (; j < end; ++j) a0 += Z[(size_t)edge_src[j] * D + f];
    float sum = (a0 + a1) + (a2 + a3);
    float v = S[(size_t)n * D + f] + inv_deg[n] * sum;
    if (ACT == 0) {
        out[(size_t)n * D + f] = fmaxf(v, 0.f);
    } else {
        float m = v;
        #pragma unroll
        for (int off = 32; off > 0; off >>= 1) m = fmaxf(m, __shfl_xor(m, off, 64));
        float e = __expf(v - m);
        float s = e;
        #pragma unroll
        for (int off = 32; off > 0; off >>= 1) s += __shfl_xor(s, off, 64);
        out[(size_t)n * D + f] = e / s;
    }
}

// ---------------------------------------------------------------------------
extern "C" void kernel_launch(void* const* d_in, const int* in_sizes, int n_in,
                              void* d_out, int out_size, void* d_ws, size_t ws_size,
                              hipStream_t stream) {
    const float* in_feat = (const float*)d_in[0];
    const int*   src     = (const int*)d_in[1];
    const int*   dst     = (const int*)d_in[2];
    const float* w1s = (const float*)d_in[3];
    const float* w1n = (const float*)d_in[4];
    const float* b1  = (const float*)d_in[5];
    const float* w2s = (const float*)d_in[6];
    const float* w2n = (const float*)d_in[7];
    const float* b2  = (const float*)d_in[8];
    const float* w3s = (const float*)d_in[9];
    const float* w3n = (const float*)d_in[10];
    const float* b3  = (const float*)d_in[11];

    const int N = N_NODES;
    const int E = in_sizes[1];

    // workspace carve (512B aligned)
    char* p = (char*)d_ws;
    auto carve = [&](size_t bytes) -> char* {
        char* q = p;
        p += (bytes + 511) & ~(size_t)511;
        return q;
    };
    float* S        = (float*)carve((size_t)N * 128 * sizeof(float));
    float* Z        = (float*)carve((size_t)N * 128 * sizeof(float));
    float* H        = (float*)carve((size_t)N * 128 * sizeof(float));
    int*   edge_src = (int*)  carve((size_t)E * sizeof(int));
    int*   row_ptr  = (int*)  carve((size_t)(N + 1) * sizeof(int));
    int*   cursor   = (int*)  carve((size_t)N * sizeof(int));
    int*   deg      = (int*)  carve((size_t)N * sizeof(int));
    float* invd     = (float*)carve((size_t)N * sizeof(float));

    // ---- CSR build ----
    hipMemsetAsync(deg, 0, (size_t)N * sizeof(int), stream);
    hist_kernel<<<(E + 255) / 256, 256, 0, stream>>>(dst, deg, E);
    scan_kernel<<<1, 1024, 0, stream>>>(deg, row_ptr, cursor, invd, N);
    fill_kernel<<<(E + 255) / 256, 256, 0, stream>>>(src, dst, cursor, edge_src, E);

    const int MB = (N + 63) / 64;   // 1563 row tiles

    // ---- Layer 1: 128 -> 128, relu ----
    gemm_kernel<<<dim3(MB, 2), 256, 0, stream>>>(in_feat, w1s, b1,      S, N, 128, 128);
    gemm_kernel<<<dim3(MB, 2), 256, 0, stream>>>(in_feat, w1n, nullptr, Z, N, 128, 128);
    agg_kernel<128, 0><<<(N + 1) / 2, 256, 0, stream>>>(S, Z, row_ptr, edge_src, invd, H, N);

    // ---- Layer 2: 128 -> 64, relu ----
    gemm_kernel<<<dim3(MB, 1), 256, 0, stream>>>(H, w2s, b2,      S, N, 128, 64);
    gemm_kernel<<<dim3(MB, 1), 256, 0, stream>>>(H, w2n, nullptr, Z, N, 128, 64);
    agg_kernel<64, 0><<<(N + 3) / 4, 256, 0, stream>>>(S, Z, row_ptr, edge_src, invd, H, N);

    // ---- Layer 3: 64 -> 64, softmax ----
    gemm_kernel<<<dim3(MB, 1), 256, 0, stream>>>(H, w3s, b3,      S, N, 64, 64);
    gemm_kernel<<<dim3(MB, 1), 256, 0, stream>>>(H, w3n, nullptr, Z, N, 64, 64);
    agg_kernel<64, 1><<<(N + 3) / 4, 256, 0, stream>>>(S, Z, row_ptr, edge_src, invd,
                                                       (float*)d_out, N);
}

// Round 2
// 800.303 us; speedup vs baseline: 1.1102x; 1.1102x over previous
//
#include <hip/hip_runtime.h>
#include <hip/hip_bf16.h>

#define N_NODES 100000

// ---------------------------------------------------------------------------
// helpers
// ---------------------------------------------------------------------------
static __device__ __forceinline__ unsigned short f2bf(float f) {
    unsigned u = __float_as_uint(f);
    unsigned r = u + 0x7FFFu + ((u >> 16) & 1u);   // round-to-nearest-even
    return (unsigned short)(r >> 16);
}

// ---------------------------------------------------------------------------
// CSR build: histogram -> scan -> fill
// ---------------------------------------------------------------------------
__global__ __launch_bounds__(256) void hist_kernel(const int* __restrict__ dst,
                                                   int* __restrict__ deg, int E) {
    int e = blockIdx.x * 256 + threadIdx.x;
    if (e < E) atomicAdd(&deg[dst[e]], 1);
}

__global__ __launch_bounds__(1024) void scan_kernel(const int* __restrict__ deg,
                                                    int* __restrict__ row_ptr,
                                                    int* __restrict__ cursor,
                                                    float* __restrict__ inv_deg, int N) {
    __shared__ int wsums[16];
    __shared__ int s_carry;
    int tid = threadIdx.x;
    int lane = tid & 63, wave = tid >> 6;
    if (tid == 0) s_carry = 0;
    __syncthreads();
    for (int base = 0; base < N; base += 1024) {
        int i = base + tid;
        int v = (i < N) ? deg[i] : 0;
        int x = v;
        #pragma unroll
        for (int off = 1; off < 64; off <<= 1) {
            int y = __shfl_up(x, off, 64);
            if (lane >= off) x += y;
        }
        if (lane == 63) wsums[wave] = x;
        __syncthreads();
        int wave_off = 0;
        for (int w = 0; w < wave; ++w) wave_off += wsums[w];
        int incl = x + wave_off;
        int excl = incl - v;
        int carry = s_carry;
        if (i < N) {
            int rp = carry + excl;
            row_ptr[i] = rp;
            cursor[i]  = rp;
            inv_deg[i] = 1.0f / (float)(v > 0 ? v : 1);
        }
        __syncthreads();
        if (tid == 1023) s_carry = carry + incl;
        __syncthreads();
    }
    if (tid == 0) row_ptr[N] = s_carry;
}

__global__ __launch_bounds__(256) void fill_kernel(const int* __restrict__ src,
                                                   const int* __restrict__ dst,
                                                   int* __restrict__ cursor,
                                                   int* __restrict__ edge_src, int E) {
    int e = blockIdx.x * 256 + threadIdx.x;
    if (e < E) {
        int d = dst[e];
        int p = atomicAdd(&cursor[d], 1);
        edge_src[p] = src[e];
    }
}

// ---------------------------------------------------------------------------
// Fused dual GEMM: given X[M,K], compute
//   S[M,NS]  = X @ Ws + bias   (fp32)
//   Zb[M,NS] = X @ Wn          (bf16)
// A-tile (64 rows x K) staged in LDS ONCE, then loop over 64-wide n-tiles of
// the concatenated [Ws | Wn]. 256 threads, 16x16 grid, 4x4 acc per thread.
// K in {64,128}, NS in {64,128}.
// ---------------------------------------------------------------------------
template <int K, int NS>
__global__ __launch_bounds__(256) void fused_gemm(const float* __restrict__ X,
                                                  const float* __restrict__ Ws,
                                                  const float* __restrict__ Wn,
                                                  const float* __restrict__ bias,
                                                  float* __restrict__ S,
                                                  unsigned short* __restrict__ Zb,
                                                  int M) {
    constexpr int KQ = K / 4;          // float4 per A row
    constexpr int NT = NS / 64;        // n-tiles per weight matrix
    constexpr int H2 = K / 64;         // 64-deep k-halves
    __shared__ float As[64][K + 4];
    __shared__ float Bs[64][68];

    int tid = threadIdx.x;
    int tr = tid >> 4, tc = tid & 15;
    int m0 = blockIdx.x * 64;

    // ---- stage A tile once ----
    #pragma unroll
    for (int idx = tid; idx < 64 * KQ; idx += 256) {
        int row = idx / KQ, q = idx % KQ;
        int gm = m0 + row;
        float4 a = (gm < M) ? *(const float4*)&X[(size_t)gm * K + 4 * q]
                            : make_float4(0.f, 0.f, 0.f, 0.f);
        *(float4*)&As[row][4 * q] = a;
    }

    for (int t = 0; t < 2 * NT; ++t) {
        const float* Wsel = (t < NT) ? Ws : Wn;
        int n0 = 64 * (t < NT ? t : t - NT);
        float acc[4][4] = {{0}};

        for (int h = 0; h < H2; ++h) {
            __syncthreads();   // protect Bs (and As on first pass)
            #pragma unroll
            for (int idx = tid; idx < 1024; idx += 256) {
                int kk = idx >> 4, nq = idx & 15;
                *(float4*)&Bs[kk][4 * nq] =
                    *(const float4*)&Wsel[(size_t)(64 * h + kk) * NS + n0 + 4 * nq];
            }
            __syncthreads();

            #pragma unroll
            for (int kq = 0; kq < 16; ++kq) {
                int kcol = 64 * h + 4 * kq;
                float4 a0 = *(const float4*)&As[4 * tr + 0][kcol];
                float4 a1 = *(const float4*)&As[4 * tr + 1][kcol];
                float4 a2 = *(const float4*)&As[4 * tr + 2][kcol];
                float4 a3 = *(const float4*)&As[4 * tr + 3][kcol];
                float4 b0 = *(const float4*)&Bs[4 * kq + 0][4 * tc];
                float4 b1 = *(const float4*)&Bs[4 * kq + 1][4 * tc];
                float4 b2 = *(const float4*)&Bs[4 * kq + 2][4 * tc];
                float4 b3 = *(const float4*)&Bs[4 * kq + 3][4 * tc];
#define FMA4(i, av, bv)                                                        \
                acc[i][0] += (av) * (bv).x; acc[i][1] += (av) * (bv).y;        \
                acc[i][2] += (av) * (bv).z; acc[i][3] += (av) * (bv).w;
                FMA4(0, a0.x, b0) FMA4(0, a0.y, b1) FMA4(0, a0.z, b2) FMA4(0, a0.w, b3)
                FMA4(1, a1.x, b0) FMA4(1, a1.y, b1) FMA4(1, a1.z, b2) FMA4(1, a1.w, b3)
                FMA4(2, a2.x, b0) FMA4(2, a2.y, b1) FMA4(2, a2.z, b2) FMA4(2, a2.w, b3)
                FMA4(3, a3.x, b0) FMA4(3, a3.y, b1) FMA4(3, a3.z, b2) FMA4(3, a3.w, b3)
#undef FMA4
            }
        }

        if (t < NT) {
            float4 bv = *(const float4*)&bias[n0 + 4 * tc];
            #pragma unroll
            for (int i = 0; i < 4; ++i) {
                int gm = m0 + 4 * tr + i;
                if (gm < M) {
                    float4 o;
                    o.x = acc[i][0] + bv.x; o.y = acc[i][1] + bv.y;
                    o.z = acc[i][2] + bv.z; o.w = acc[i][3] + bv.w;
                    *(float4*)&S[(size_t)gm * NS + n0 + 4 * tc] = o;
                }
            }
        } else {
            #pragma unroll
            for (int i = 0; i < 4; ++i) {
                int gm = m0 + 4 * tr + i;
                if (gm < M) {
                    uint2 o;
                    o.x = (unsigned)f2bf(acc[i][0]) | ((unsigned)f2bf(acc[i][1]) << 16);
                    o.y = (unsigned)f2bf(acc[i][2]) | ((unsigned)f2bf(acc[i][3]) << 16);
                    *(uint2*)&Zb[(size_t)gm * NS + n0 + 4 * tc] = o;
                }
            }
        }
    }
}

// ---------------------------------------------------------------------------
// Aggregate with bf16 Z: out[n,f] = act( S[n,f] + inv_deg[n]*sum Z[src,f] )
// One thread handles 2 features (bfloat162 loads). Group = D/2 lanes.
// ACT: 0 = relu (fp32 out), 1 = softmax over D==64 (group = half-wave)
// ---------------------------------------------------------------------------
template <int D, int ACT>
__global__ __launch_bounds__(256) void agg_kernel(const float* __restrict__ S,
                                                  const unsigned int* __restrict__ Zu,
                                                  const int* __restrict__ row_ptr,
                                                  const int* __restrict__ edge_src,
                                                  const float* __restrict__ inv_deg,
                                                  float* __restrict__ out, int N) {
    constexpr int G  = D / 2;          // lanes per node
    constexpr int NG = 256 / G;        // nodes per block
    int tid = threadIdx.x;
    int g = tid / G, f2 = tid % G;
    int n = blockIdx.x * NG + g;
    if (n >= N) return;
    int beg = row_ptr[n], end = row_ptr[n + 1];

    float ax0 = 0.f, ay0 = 0.f, ax1 = 0.f, ay1 = 0.f;
    float ax2 = 0.f, ay2 = 0.f, ax3 = 0.f, ay3 = 0.f;
    int j = beg;
    for (; j + 3 < end; j += 4) {
        int s0 = edge_src[j + 0], s1 = edge_src[j + 1];
        int s2 = edge_src[j + 2], s3 = edge_src[j + 3];
        unsigned u0 = Zu[(size_t)s0 * G + f2];
        unsigned u1 = Zu[(size_t)s1 * G + f2];
        unsigned u2 = Zu[(size_t)s2 * G + f2];
        unsigned u3 = Zu[(size_t)s3 * G + f2];
        ax0 += __uint_as_float(u0 << 16); ay0 += __uint_as_float(u0 & 0xFFFF0000u);
        ax1 += __uint_as_float(u1 << 16); ay1 += __uint_as_float(u1 & 0xFFFF0000u);
        ax2 += __uint_as_float(u2 << 16); ay2 += __uint_as_float(u2 & 0xFFFF0000u);
        ax3 += __uint_as_float(u3 << 16); ay3 += __uint_as_float(u3 & 0xFFFF0000u);
    }
    for (; j < end; ++j) {
        unsigned u = Zu[(size_t)edge_src[j] * G + f2];
        ax0 += __uint_as_float(u << 16); ay0 += __uint_as_float(u & 0xFFFF0000u);
    }
    float sx = (ax0 + ax1) + (ax2 + ax3);
    float sy = (ay0 + ay1) + (ay2 + ay3);
    float id = inv_deg[n];
    float2 sv = ((const float2*)(S + (size_t)n * D))[f2];
    float vx = sv.x + id * sx;
    float vy = sv.y + id * sy;

    if (ACT == 0) {
        float2 o; o.x = fmaxf(vx, 0.f); o.y = fmaxf(vy, 0.f);
        ((float2*)(out + (size_t)n * D))[f2] = o;
    } else {
        // softmax over 64 features spread across 32 lanes x 2
        float m = fmaxf(vx, vy);
        #pragma unroll
        for (int off = 16; off > 0; off >>= 1) m = fmaxf(m, __shfl_xor(m, off, 64));
        float ex = __expf(vx - m), ey = __expf(vy - m);
        float s = ex + ey;
        #pragma unroll
        for (int off = 16; off > 0; off >>= 1) s += __shfl_xor(s, off, 64);
        float inv = 1.0f / s;
        float2 o; o.x = ex * inv; o.y = ey * inv;
        ((float2*)(out + (size_t)n * D))[f2] = o;
    }
}

// ---------------------------------------------------------------------------
extern "C" void kernel_launch(void* const* d_in, const int* in_sizes, int n_in,
                              void* d_out, int out_size, void* d_ws, size_t ws_size,
                              hipStream_t stream) {
    const float* in_feat = (const float*)d_in[0];
    const int*   src     = (const int*)d_in[1];
    const int*   dst     = (const int*)d_in[2];
    const float* w1s = (const float*)d_in[3];
    const float* w1n = (const float*)d_in[4];
    const float* b1  = (const float*)d_in[5];
    const float* w2s = (const float*)d_in[6];
    const float* w2n = (const float*)d_in[7];
    const float* b2  = (const float*)d_in[8];
    const float* w3s = (const float*)d_in[9];
    const float* w3n = (const float*)d_in[10];
    const float* b3  = (const float*)d_in[11];

    const int N = N_NODES;
    const int E = in_sizes[1];

    char* p = (char*)d_ws;
    auto carve = [&](size_t bytes) -> char* {
        char* q = p;
        p += (bytes + 511) & ~(size_t)511;
        return q;
    };
    float*          S        = (float*)         carve((size_t)N * 128 * sizeof(float));
    unsigned short* Zb       = (unsigned short*)carve((size_t)N * 128 * sizeof(unsigned short));
    float*          H        = (float*)         carve((size_t)N * 128 * sizeof(float));
    int*            edge_src = (int*)           carve((size_t)E * sizeof(int));
    int*            row_ptr  = (int*)           carve((size_t)(N + 1) * sizeof(int));
    int*            cursor   = (int*)           carve((size_t)N * sizeof(int));
    int*            deg      = (int*)           carve((size_t)N * sizeof(int));
    float*          invd     = (float*)         carve((size_t)N * sizeof(float));

    // ---- CSR build ----
    hipMemsetAsync(deg, 0, (size_t)N * sizeof(int), stream);
    hist_kernel<<<(E + 255) / 256, 256, 0, stream>>>(dst, deg, E);
    scan_kernel<<<1, 1024, 0, stream>>>(deg, row_ptr, cursor, invd, N);
    fill_kernel<<<(E + 255) / 256, 256, 0, stream>>>(src, dst, cursor, edge_src, E);

    const int MB = (N + 63) / 64;

    // ---- Layer 1: 128 -> 128, relu ----
    fused_gemm<128, 128><<<MB, 256, 0, stream>>>(in_feat, w1s, w1n, b1, S, Zb, N);
    agg_kernel<128, 0><<<(N + 3) / 4, 256, 0, stream>>>(S, (const unsigned*)Zb,
                                                        row_ptr, edge_src, invd, H, N);

    // ---- Layer 2: 128 -> 64, relu ----
    fused_gemm<128, 64><<<MB, 256, 0, stream>>>(H, w2s, w2n, b2, S, Zb, N);
    agg_kernel<64, 0><<<(N + 7) / 8, 256, 0, stream>>>(S, (const unsigned*)Zb,
                                                       row_ptr, edge_src, invd, H, N);

    // ---- Layer 3: 64 -> 64, softmax ----
    fused_gemm<64, 64><<<MB, 256, 0, stream>>>(H, w3s, w3n, b3, S, Zb, N);
    agg_kernel<64, 1><<<(N + 7) / 8, 256, 0, stream>>>(S, (const unsigned*)Zb,
                                                       row_ptr, edge_src, invd,
                                                       (float*)d_out, N);
}